// Round 10
// baseline (386.765 us; speedup 1.0000x reference)
//
#include <hip/hip_runtime.h>
#include <math.h>

// Problem constants (match reference)
#define NN 50000   // nodes
#define EE 800000  // edges
#define FF 128     // node features
#define CC 11      // spline coeffs per feature (G+K)
#define O2 256     // combined outputs: 128 src-proj + 128 dst-proj
#define KT 1536    // true K: 128 features x 12 slots (11 spline + silu)
#define NKC 8      // K-chunks of 192 (16 features x 12)
#define AROW 200   // A-tile row in shorts (192 + 8 pad): 400 B = 100 dw = 4 mod 32 banks (2-way, free)
#define NPB 782    // proj blocks: ceil(NN/64)
#define NCB 782    // count blocks: ceil(EE/(256*4))

typedef __attribute__((ext_vector_type(8))) short short8;
typedef __attribute__((ext_vector_type(4))) float f32x4;
typedef unsigned int uint;
typedef unsigned short ushort;
typedef unsigned long long ull;

__device__ __forceinline__ ushort bf16_rne(float v) {
  uint u = __float_as_uint(v);
  u = u + 0x7FFFu + ((u >> 16) & 1u);
  return (ushort)(u >> 16);
}
__device__ __forceinline__ float bf_lo(uint u) { return __uint_as_float(u << 16); }
__device__ __forceinline__ float bf_hi(uint u) { return __uint_as_float(u & 0xffff0000u); }

// Repack weights to B^T bf16 [o2][k] + zero deg (fused, removes memset dispatch)
__global__ __launch_bounds__(256) void repack_zero_kernel(
    const float* __restrict__ bws, const float* __restrict__ sws,
    const float* __restrict__ bwd, const float* __restrict__ swd,
    ushort* __restrict__ Wh, int* __restrict__ deg) {
  int idx = blockIdx.x * 256 + threadIdx.x;
  if (idx < NN) deg[idx] = 0;
  if (idx >= O2 * KT) return;
  int col = idx / KT;
  int kk = idx - col * KT;
  int f = kk / 12;
  int ch = kk - f * 12;
  const float* bw = (col < 128) ? bws : bwd;
  const float* sw = (col < 128) ? sws : swd;
  int o = col & 127;
  float v = (ch == 11) ? bw[(size_t)o * FF + f] : sw[((size_t)o * FF + f) * CC + ch];
  Wh[idx] = bf16_rne(v);
}

// Fused dispatch, interleaved: even blocks = MFMA projection, odd = degree
// count (4 edges/thread, int4). Count blocks are short so their CU slots
// recycle and count rides in proj's latency shadow.
//
// Projection: block = 64 nodes x 256 cols, 4 waves. Closed-form cardinal
// cubic basis; each feature's 12-slot bf16 row is built IN REGISTERS via a
// branchless 64-bit funnel shift (the 4 nonzero weights W placed at bit
// offset 16*(j-3) of the 192-bit row, slot 11 = silu, out-of-range j -> 0),
// then stored as 6 contiguous uint4 — no scattered ds_write_b16, no zero
// fill, conflict-free by construction. K chunked by 192, double-buffered
// A-tile, one barrier per chunk. Output bf16-packed projB[node][p]:
// p=q*16+m holds cols (q*32+m, q*32+16+m).
__global__ __launch_bounds__(256) void proj_count_kernel(
    const float* __restrict__ x, const ushort* __restrict__ Wh,
    uint* __restrict__ projB, const int* __restrict__ ei, int* __restrict__ deg) {
  __shared__ ushort Ah[2][64][AROW];  // 51.2 KB
  const int b = blockIdx.x;
  if (b & 1) {  // ---- count part ----
    int base = ((b >> 1) * 256 + threadIdx.x) * 4;
    if (base + 3 < EE) {
      int4 dd = *(const int4*)(ei + EE + base);
      atomicAdd(&deg[dd.x], 1);
      atomicAdd(&deg[dd.y], 1);
      atomicAdd(&deg[dd.z], 1);
      atomicAdd(&deg[dd.w], 1);
    } else {
      for (int j = 0; j < 4 && base + j < EE; ++j) atomicAdd(&deg[ei[EE + base + j]], 1);
    }
    return;
  }
  const int t = threadIdx.x;
  const int lane = t & 63;
  const int w = t >> 6;      // wave 0..3
  const int m = lane & 15;
  const int quad = lane >> 4;
  const int block0 = (b >> 1) * 64;
  const int gn = block0 + lane;  // staging: node = lane, feature group = wave
  const bool valid = (gn < NN);

  auto stage = [&](float4 xvv, ushort(*buf)[AROW]) {
    float xa[4] = {xvv.x, xvv.y, xvv.z, xvv.w};
    uint ou[24];
#pragma unroll
    for (int jf = 0; jf < 4; ++jf) {
      float xv = xa[jf];
      ushort s16 = bf16_rne(xv / (1.f + __expf(-xv)));  // silu
      float u = fmaf(xv, 4.f, 7.f);
      float fj = floorf(u);
      int j = (int)fj;
      float tt = u - fj;
      float t2 = tt * tt, t3 = t2 * tt;
      float w0 = (1.f / 6.f) * (1.f - 3.f * tt + 3.f * t2 - t3);
      float w1 = (1.f / 6.f) * (4.f - 6.f * t2 + 3.f * t3);
      float w2 = (1.f / 6.f) * (1.f + 3.f * tt + 3.f * t2 - 3.f * t3);
      float w3 = (1.f / 6.f) * t3;
      ull W = (ull)((uint)bf16_rne(w0) | ((uint)bf16_rne(w1) << 16)) |
              ((ull)((uint)bf16_rne(w2) | ((uint)bf16_rne(w3) << 16)) << 32);
      if ((uint)j > 13u) W = 0ull;   // x outside extended grid -> all-zero bases
      int P16 = (j - 3) * 16;        // bit offset of W within the 192-bit row
#pragma unroll
      for (int t6 = 0; t6 < 6; ++t6) {
        int bs = 32 * t6 - P16;
        uint lo = 0u;
        if (bs >= 0) {
          if (bs < 64) lo = (uint)(W >> bs);
        } else if (bs > -32) {
          lo = (uint)(W << (-bs));
        }
        ou[jf * 6 + t6] = lo;
      }
      // slot 11 = silu (also clips any weight that landed on slot 11)
      ou[jf * 6 + 5] = (ou[jf * 6 + 5] & 0xFFFFu) | ((uint)s16 << 16);
    }
    uint4* dst = (uint4*)&buf[lane][w * 48];  // 96 B contiguous, 16B-aligned
#pragma unroll
    for (int i = 0; i < 6; ++i)
      dst[i] = make_uint4(ou[i * 4], ou[i * 4 + 1], ou[i * 4 + 2], ou[i * 4 + 3]);
  };

  f32x4 acc[4][4];
#pragma unroll
  for (int r = 0; r < 4; ++r)
#pragma unroll
    for (int c = 0; c < 4; ++c) acc[r][c] = (f32x4)(0.f);

  const float4 zero4 = make_float4(0.f, 0.f, 0.f, 0.f);
  float4 xv0 = valid ? *(const float4*)(x + (size_t)gn * FF + w * 4) : zero4;
  stage(xv0, Ah[0]);
  float4 xv_next = valid ? *(const float4*)(x + (size_t)gn * FF + 16 + w * 4) : zero4;
  __syncthreads();

#pragma unroll 2
  for (int kc = 0; kc < NKC; ++kc) {
    float4 xv_pf = zero4;
    if (kc + 2 < NKC && valid)
      xv_pf = *(const float4*)(x + (size_t)gn * FF + (kc + 2) * 16 + w * 4);
    short8 bh_c[4], bh_n[4];
#pragma unroll
    for (int c = 0; c < 4; ++c)
      bh_c[c] = *(const short8*)(Wh + (size_t)(w * 64 + c * 16 + m) * KT +
                                 kc * 192 + quad * 8);
    if (kc + 1 < NKC) stage(xv_next, Ah[(kc + 1) & 1]);
#pragma unroll
    for (int sk = 0; sk < 6; ++sk) {
      if (sk < 5) {
#pragma unroll
        for (int c = 0; c < 4; ++c)
          bh_n[c] = *(const short8*)(Wh + (size_t)(w * 64 + c * 16 + m) * KT +
                                     kc * 192 + (sk + 1) * 32 + quad * 8);
      }
      short8 a[4];
#pragma unroll
      for (int r = 0; r < 4; ++r)
        a[r] = *(const short8*)(&Ah[kc & 1][r * 16 + m][sk * 32 + quad * 8]);
#pragma unroll
      for (int r = 0; r < 4; ++r)
#pragma unroll
        for (int c = 0; c < 4; ++c)
          acc[r][c] = __builtin_amdgcn_mfma_f32_16x16x32_bf16(a[r], bh_c[c], acc[r][c], 0, 0, 0);
#pragma unroll
      for (int c = 0; c < 4; ++c) bh_c[c] = bh_n[c];
    }
    __syncthreads();
    xv_next = xv_pf;
  }
  // epilogue: C/D layout col=lane&15, row=quad*4+reg (verified m89/m91).
  // pack c-pairs: p = q*16 + m, q = 2w + cp -> cols (q*32+m, q*32+16+m)
#pragma unroll
  for (int r = 0; r < 4; ++r) {
#pragma unroll
    for (int reg = 0; reg < 4; ++reg) {
      int nd = block0 + r * 16 + quad * 4 + reg;
      if (nd < NN) {
#pragma unroll
        for (int cp = 0; cp < 2; ++cp) {
          int q = 2 * w + cp;
          uint val = (uint)bf16_rne(acc[r][2 * cp][reg]) |
                     ((uint)bf16_rne(acc[r][2 * cp + 1][reg]) << 16);
          projB[(size_t)nd * 128 + q * 16 + m] = val;
        }
      }
    }
  }
}

// ---- CSR build ----
__global__ __launch_bounds__(256) void scanA_kernel(
    const int* __restrict__ deg, int* __restrict__ ex, int* __restrict__ partial) {
  __shared__ int sd[256];
  int t = threadIdx.x;
  int idx = blockIdx.x * 256 + t;
  int v = (idx < NN) ? deg[idx] : 0;
  sd[t] = v;
  __syncthreads();
#pragma unroll
  for (int off = 1; off < 256; off <<= 1) {
    int add = (t >= off) ? sd[t - off] : 0;
    __syncthreads();
    sd[t] += add;
    __syncthreads();
  }
  if (idx < NN) ex[idx] = sd[t] - v;
  if (t == 255) partial[blockIdx.x] = sd[255];
}

__global__ __launch_bounds__(256) void scanB_kernel(
    const int* __restrict__ partial, int* __restrict__ poff, int nblk) {
  __shared__ int sd[256];
  int t = threadIdx.x;
  int v = (t < nblk) ? partial[t] : 0;
  sd[t] = v;
  __syncthreads();
#pragma unroll
  for (int off = 1; off < 256; off <<= 1) {
    int add = (t >= off) ? sd[t - off] : 0;
    __syncthreads();
    sd[t] += add;
    __syncthreads();
  }
  if (t < nblk) poff[t] = sd[t] - v;
}

__global__ __launch_bounds__(256) void scanC_kernel(
    const int* __restrict__ ex, const int* __restrict__ poff,
    int* __restrict__ row_ptr, int* __restrict__ cur) {
  int idx = blockIdx.x * 256 + threadIdx.x;
  if (idx < NN) {
    int v = ex[idx] + poff[idx >> 8];
    row_ptr[idx] = v;
    cur[idx] = v;
  }
  if (idx == 0) row_ptr[NN] = EE;
}

// 2 edges/thread, int2 loads; store SRC id directly
__global__ __launch_bounds__(256) void fill_kernel(
    const int* __restrict__ ei, int* __restrict__ cur, int* __restrict__ scsr) {
  int base = (blockIdx.x * 256 + threadIdx.x) * 2;
  if (base + 1 < EE) {
    int2 ss = *(const int2*)(ei + base);
    int2 dd = *(const int2*)(ei + EE + base);
    int p0 = atomicAdd(&cur[dd.x], 1);
    scsr[p0] = ss.x;
    int p1 = atomicAdd(&cur[dd.y], 1);
    scsr[p1] = ss.y;
  } else if (base < EE) {
    int s = ei[base], d = ei[EE + base];
    scsr[atomicAdd(&cur[d], 1)] = s;
  }
}

// Per-dst aggregation: one wave per dst, 4 edges in flight (16-lane groups),
// 2-deep gather pipeline (src idx 3 ahead, row data 2 ahead).
// Lane l: group g=l>>4, m=l&15 -> uint4 = p 4m..4m+3 (head m>>2 only) ->
// score reduce = 2 shfls. Cross-group combine once; fused epilogue.
__global__ __launch_bounds__(256) void aggr_kernel(
    const uint* __restrict__ projB, const int* __restrict__ scsr,
    const int* __restrict__ row_ptr, const float* __restrict__ av,
    const float* __restrict__ x, const float* __restrict__ bias,
    const float* __restrict__ pa, float* __restrict__ out) {
  int d = blockIdx.x * 4 + (threadIdx.x >> 6);
  if (d >= NN) return;
  int l = threadIdx.x & 63;
  int g = l >> 4, m = l & 15;
  const uint4* pb4 = (const uint4*)projB;
  uint4 dpu = pb4[(size_t)d * 32 + 16 + m];
  uint du[4] = {dpu.x, dpu.y, dpu.z, dpu.w};
  float dplo[4], dphi[4], avlo[4], avhi[4];
  int cl[4];
#pragma unroll
  for (int j = 0; j < 4; ++j) {
    dplo[j] = bf_lo(du[j]);
    dphi[j] = bf_hi(du[j]);
    int p = 4 * m + j;
    cl[j] = ((p >> 4) << 5) + (p & 15);
    avlo[j] = av[cl[j]];
    avhi[j] = av[cl[j] + 16];
  }
  int i0 = row_ptr[d], i1 = row_ptr[d + 1];
  float acl[4] = {0.f, 0.f, 0.f, 0.f}, ach[4] = {0.f, 0.f, 0.f, 0.f};
  float den = 0.f;
  int i = i0 + g;
  if (i < i1) {
    int s0 = scsr[i];
    int s1 = (i + 4 < i1) ? scsr[i + 4] : s0;
    int s2 = (i + 8 < i1) ? scsr[i + 8] : s1;
    uint4 U0 = pb4[(size_t)s0 * 32 + m];
    uint4 U1 = pb4[(size_t)s1 * 32 + m];
    for (; i < i1; i += 4) {
      int s3 = (i + 12 < i1) ? scsr[i + 12] : s2;
      uint4 U2 = pb4[(size_t)s2 * 32 + m];  // 2-ahead, issues immediately
      uint uu[4] = {U0.x, U0.y, U0.z, U0.w};
      float slo[4], shi[4];
      float vp = 0.f;
#pragma unroll
      for (int j = 0; j < 4; ++j) {
        slo[j] = bf_lo(uu[j]);
        shi[j] = bf_hi(uu[j]);
        float v0 = slo[j] + dplo[j];
        float v1 = shi[j] + dphi[j];
        v0 = (v0 >= 0.f) ? v0 : 0.2f * v0;
        v1 = (v1 >= 0.f) ? v1 : 0.2f * v1;
        vp = fmaf(v0, avlo[j], vp);
        vp = fmaf(v1, avhi[j], vp);
      }
      vp += __shfl_xor(vp, 1, 64);  // head-local reduce (4-lane subgroup)
      vp += __shfl_xor(vp, 2, 64);
      float e = __expf(vp);
#pragma unroll
      for (int j = 0; j < 4; ++j) {
        acl[j] = fmaf(e, slo[j], acl[j]);
        ach[j] = fmaf(e, shi[j], ach[j]);
      }
      den += e;
      U0 = U1;
      U1 = U2;
      s2 = s3;
    }
  }
  // combine the 4 edge-groups (heads preserved: lanes with same m align)
#pragma unroll
  for (int off = 16; off < 64; off <<= 1) {
    den += __shfl_xor(den, off, 64);
#pragma unroll
    for (int j = 0; j < 4; ++j) {
      acl[j] += __shfl_xor(acl[j], off, 64);
      ach[j] += __shfl_xor(ach[j], off, 64);
    }
  }
  if (g == 0) {
    float a = pa[0];
    float r = 1.f / (den + 1e-16f);
#pragma unroll
    for (int j = 0; j < 4; ++j) {
      float o0 = acl[j] * r + x[(size_t)d * FF + cl[j]] + bias[cl[j]];
      float o1 = ach[j] * r + x[(size_t)d * FF + cl[j] + 16] + bias[cl[j] + 16];
      out[(size_t)d * FF + cl[j]] = (o0 >= 0.f) ? o0 : a * o0;
      out[(size_t)d * FF + cl[j] + 16] = (o1 >= 0.f) ? o1 : a * o1;
    }
  }
}

extern "C" void kernel_launch(void* const* d_in, const int* in_sizes, int n_in,
                              void* d_out, int out_size, void* d_ws, size_t ws_size,
                              hipStream_t stream) {
  const float* x = (const float*)d_in[0];
  const int* ei = (const int*)d_in[1];
  const float* bws = (const float*)d_in[2];
  const float* sws = (const float*)d_in[3];
  const float* bwd = (const float*)d_in[4];
  const float* swd = (const float*)d_in[5];
  const float* av = (const float*)d_in[6];
  const float* bias = (const float*)d_in[7];
  const float* pa = (const float*)d_in[8];

  // ws layout: Wh | projB | deg | ex | cur | row_ptr | partial | poff | scsr
  ushort* Wh = (ushort*)d_ws;
  uint* projB = (uint*)(Wh + (size_t)O2 * KT);
  int* deg = (int*)(projB + (size_t)NN * 128);
  int* ex = deg + NN;
  int* cur = ex + NN;
  int* row_ptr = cur + NN;         // NN+1 entries
  int* partial = row_ptr + NN + 1;
  int* poff = partial + 256;
  int* scsr = poff + 256;

  const int NB = (NN + 255) / 256;  // 196 scan blocks

  repack_zero_kernel<<<(O2 * KT + 255) / 256, 256, 0, stream>>>(bws, sws, bwd, swd, Wh, deg);
  proj_count_kernel<<<NPB + NCB, 256, 0, stream>>>(x, Wh, projB, ei, deg);
  scanA_kernel<<<NB, 256, 0, stream>>>(deg, ex, partial);
  scanB_kernel<<<1, 256, 0, stream>>>(partial, poff, NB);
  scanC_kernel<<<NB, 256, 0, stream>>>(ex, poff, row_ptr, cur);
  fill_kernel<<<(EE / 2 + 255) / 256, 256, 0, stream>>>(ei, cur, scsr);
  aggr_kernel<<<(NN + 3) / 4, 256, 0, stream>>>(projB, scsr, row_ptr, av, x, bias, pa,
                                                (float*)d_out);
}